// Round 1
// baseline (30.895 us; speedup 1.0000x reference)
//
#include <hip/hip_runtime.h>

#define BS 8
#define NN 1024
#define JJ 4
#define FF 32
#define NC 2

// y[b][m][j][c] = sum_f x[b,m,f] * fc_w[c, j*FF+f]
// One thread per (b,m,j); computes both classes c=0,1.
__global__ void __launch_bounds__(256) compute_y_kernel(
    const float* __restrict__ x, const float* __restrict__ fc_w,
    float* __restrict__ y) {
    int idx = blockIdx.x * blockDim.x + threadIdx.x;  // over BS*NN*JJ = 32768
    if (idx >= BS * NN * JJ) return;
    int j  = idx & (JJ - 1);
    int bm = idx >> 2;                 // b*NN + m
    const float* xr = x + (size_t)bm * FF;
    const float* w0 = fc_w + 0 * (JJ * FF) + j * FF;
    const float* w1 = fc_w + 1 * (JJ * FF) + j * FF;
    float a0 = 0.f, a1 = 0.f;
#pragma unroll
    for (int f = 0; f < FF; ++f) {
        float xv = xr[f];
        a0 += xv * w0[f];
        a1 += xv * w1[f];
    }
    // layout: y[((b*NN+m)*JJ + j)*NC + c]  -> float2 at index idx
    reinterpret_cast<float2*>(y)[idx] = make_float2(a0, a1);
}

// out[b,n,c] = sum_m sum_j WW[b,n,m,j] * y[b,m,j,c] + fc_b[c]
// One wave (64 lanes) per (b,n); 4 waves per block.
__global__ void __launch_bounds__(256) reduce_out_kernel(
    const float* __restrict__ WW, const float* __restrict__ y,
    const float* __restrict__ fc_b, float* __restrict__ out) {
    const int wave = threadIdx.x >> 6;
    const int lane = threadIdx.x & 63;
    const int gid  = blockIdx.x * 4 + wave;   // b*NN + n, in [0, BS*NN)
    const int b    = gid >> 10;

    const float4* W4 = reinterpret_cast<const float4*>(WW + (size_t)gid * (NN * JJ));
    const float4* Y4 = reinterpret_cast<const float4*>(y + (size_t)b * (NN * JJ * NC));

    float a0 = 0.f, a1 = 0.f;
#pragma unroll 4
    for (int m = lane; m < NN; m += 64) {
        float4 w  = W4[m];          // WW[b,n,m,0..3]
        float4 y0 = Y4[m * 2];      // y[m][j0][c0], y[m][j0][c1], y[m][j1][c0], y[m][j1][c1]
        float4 y1 = Y4[m * 2 + 1];  // y[m][j2][c0], y[m][j2][c1], y[m][j3][c0], y[m][j3][c1]
        a0 += w.x * y0.x + w.y * y0.z + w.z * y1.x + w.w * y1.z;
        a1 += w.x * y0.y + w.y * y0.w + w.z * y1.y + w.w * y1.w;
    }
#pragma unroll
    for (int off = 32; off > 0; off >>= 1) {
        a0 += __shfl_down(a0, off, 64);
        a1 += __shfl_down(a1, off, 64);
    }
    if (lane == 0) {
        out[(size_t)gid * NC + 0] = a0 + fc_b[0];
        out[(size_t)gid * NC + 1] = a1 + fc_b[1];
    }
}

extern "C" void kernel_launch(void* const* d_in, const int* in_sizes, int n_in,
                              void* d_out, int out_size, void* d_ws, size_t ws_size,
                              hipStream_t stream) {
    const float* WW   = (const float*)d_in[0];  // (BS, NN, NN, JJ) fp32
    const float* x    = (const float*)d_in[1];  // (BS, NN, FF) fp32
    const float* fc_w = (const float*)d_in[2];  // (NC, JJ*FF) fp32
    const float* fc_b = (const float*)d_in[3];  // (NC,) fp32
    float* out = (float*)d_out;                 // (BS, NN, NC) fp32
    float* y   = (float*)d_ws;                  // BS*NN*JJ*NC floats = 256 KB scratch

    // Kernel 1: y = x @ fc_w^T (per j-slice), tiny
    {
        int total = BS * NN * JJ;
        compute_y_kernel<<<(total + 255) / 256, 256, 0, stream>>>(x, fc_w, y);
    }
    // Kernel 2: single pass over WW (134 MB), one wave per (b,n)
    {
        int blocks = (BS * NN) / 4;  // 2048
        reduce_out_kernel<<<blocks, 256, 0, stream>>>(WW, y, fc_b, out);
    }
}

// Round 2
// 30.586 us; speedup vs baseline: 1.0101x; 1.0101x over previous
//
#include <hip/hip_runtime.h>

#define BS 8
#define NN 1024
#define JJ 4
#define FF 32
#define NC 2

typedef float f4v __attribute__((ext_vector_type(4)));

// y[b][m][j][c] = sum_f x[b,m,f] * fc_w[c, j*FF+f]
// Deinterleaved output:
//   yA[(b*NN+m)] = float4(j0c0, j0c1, j1c0, j1c1)
//   yB[(b*NN+m)] = float4(j2c0, j2c1, j3c0, j3c1)
// One thread per (b,m,j); computes both classes.
__global__ void __launch_bounds__(256) compute_y_kernel(
    const float* __restrict__ x, const float* __restrict__ fc_w,
    float2* __restrict__ yA, float2* __restrict__ yB) {
    int idx = blockIdx.x * blockDim.x + threadIdx.x;  // over BS*NN*JJ = 32768
    if (idx >= BS * NN * JJ) return;
    int j  = idx & (JJ - 1);
    int bm = idx >> 2;                 // b*NN + m
    const float* xr = x + (size_t)bm * FF;
    const float* w0 = fc_w + 0 * (JJ * FF) + j * FF;
    const float* w1 = fc_w + 1 * (JJ * FF) + j * FF;
    float a0 = 0.f, a1 = 0.f;
#pragma unroll
    for (int f = 0; f < FF; ++f) {
        float xv = xr[f];
        a0 += xv * w0[f];
        a1 += xv * w1[f];
    }
    float2 v = make_float2(a0, a1);
    if (j < 2) yA[bm * 2 + j]       = v;
    else       yB[bm * 2 + (j - 2)] = v;
}

// out[b,n,c] = sum_m sum_j WW[b,n,m,j] * y[b,m,j,c] + fc_b[c]
// Block = 256 threads = 4 waves; each wave handles 2 rows -> 8 rows/block.
// 1024 blocks total; each block stages y[b] (32 KB) into LDS once.
__global__ void __launch_bounds__(256) reduce_out_kernel(
    const float* __restrict__ WW, const float4* __restrict__ yA,
    const float4* __restrict__ yB, const float* __restrict__ fc_b,
    float* __restrict__ out) {
    __shared__ float4 lyA[NN];
    __shared__ float4 lyB[NN];

    const int blk  = blockIdx.x;          // 0..1023
    const int b    = blk >> 7;            // 128 blocks per batch element
    const int wave = threadIdx.x >> 6;
    const int lane = threadIdx.x & 63;

    // Stage y[b] into LDS (coalesced, linear)
    for (int i = threadIdx.x; i < NN; i += 256) {
        lyA[i] = yA[(size_t)b * NN + i];
        lyB[i] = yB[(size_t)b * NN + i];
    }
    __syncthreads();

    const int row0 = blk * 8 + wave * 2;  // global row = b*NN + n
    const f4v* W0 = reinterpret_cast<const f4v*>(WW) + (size_t)row0 * NN;
    const f4v* W1 = W0 + NN;

    float a00 = 0.f, a01 = 0.f, a10 = 0.f, a11 = 0.f;
#pragma unroll 4
    for (int m = lane; m < NN; m += 64) {
        f4v w0 = __builtin_nontemporal_load(W0 + m);
        f4v w1 = __builtin_nontemporal_load(W1 + m);
        float4 ya = lyA[m];
        float4 yb = lyB[m];
        a00 += w0.x * ya.x + w0.y * ya.z + w0.z * yb.x + w0.w * yb.z;
        a01 += w0.x * ya.y + w0.y * ya.w + w0.z * yb.y + w0.w * yb.w;
        a10 += w1.x * ya.x + w1.y * ya.z + w1.z * yb.x + w1.w * yb.z;
        a11 += w1.x * ya.y + w1.y * ya.w + w1.z * yb.y + w1.w * yb.w;
    }
#pragma unroll
    for (int off = 32; off > 0; off >>= 1) {
        a00 += __shfl_down(a00, off, 64);
        a01 += __shfl_down(a01, off, 64);
        a10 += __shfl_down(a10, off, 64);
        a11 += __shfl_down(a11, off, 64);
    }
    if (lane == 0) {
        float b0 = fc_b[0], b1 = fc_b[1];
        out[(size_t)row0 * NC + 0] = a00 + b0;
        out[(size_t)row0 * NC + 1] = a01 + b1;
        out[(size_t)(row0 + 1) * NC + 0] = a10 + b0;
        out[(size_t)(row0 + 1) * NC + 1] = a11 + b1;
    }
}

extern "C" void kernel_launch(void* const* d_in, const int* in_sizes, int n_in,
                              void* d_out, int out_size, void* d_ws, size_t ws_size,
                              hipStream_t stream) {
    const float* WW   = (const float*)d_in[0];  // (BS, NN, NN, JJ) fp32
    const float* x    = (const float*)d_in[1];  // (BS, NN, FF) fp32
    const float* fc_w = (const float*)d_in[2];  // (NC, JJ*FF) fp32
    const float* fc_b = (const float*)d_in[3];  // (NC,) fp32
    float* out = (float*)d_out;                 // (BS, NN, NC) fp32

    // workspace: yA (BS*NN float4 = 128 KB) then yB (128 KB)
    float* ws  = (float*)d_ws;
    float2* yA2 = (float2*)ws;
    float2* yB2 = (float2*)(ws + (size_t)BS * NN * 4);

    // Kernel 1: y = x @ fc_w^T (per j-slice), tiny
    {
        int total = BS * NN * JJ;
        compute_y_kernel<<<(total + 255) / 256, 256, 0, stream>>>(x, fc_w, yA2, yB2);
    }
    // Kernel 2: single pass over WW (134 MB), 2 rows per wave, y in LDS
    {
        int blocks = (BS * NN) / 8;  // 1024
        reduce_out_kernel<<<blocks, 256, 0, stream>>>(
            WW, (const float4*)yA2, (const float4*)yB2, fc_b, out);
    }
}